// Round 1
// baseline (12543.203 us; speedup 1.0000x reference)
//
#include <hip/hip_runtime.h>

#define TT   512
#define IDIM 64
#define HDIM 256

typedef short  short8  __attribute__((ext_vector_type(8)));
typedef short  short4v __attribute__((ext_vector_type(4)));
typedef float  f32x4   __attribute__((ext_vector_type(4)));

__device__ __forceinline__ short f2bf(float f) {
    unsigned u = __float_as_uint(f);
    u = u + 0x7FFFu + ((u >> 16) & 1u);   // round-to-nearest-even
    return (short)(u >> 16);
}
__device__ __forceinline__ float bf2f(short h) {
    return __uint_as_float(((unsigned)(unsigned short)h) << 16);
}
__device__ __forceinline__ float sigm(float x)  { return 1.0f / (1.0f + __expf(-x)); }
__device__ __forceinline__ float tanh_(float x) { return 2.0f / (1.0f + __expf(-2.0f * x)) - 1.0f; }

// 256 persistent workgroups = 16 batch-groups (16 rows) x 16 hidden-chunks (16 units).
// Clique = the 16 wgs sharing a batch-group; exchange h via global + flag barrier.
// blk swizzle puts a clique on one XCD under round-robin dispatch (perf heuristic only).
__global__ __launch_bounds__(256, 1) void lstm_fused(
    const float* __restrict__ x,
    const float* __restrict__ Wih0, const float* __restrict__ Whh0,
    const float* __restrict__ bih0, const float* __restrict__ bhh0,
    const float* __restrict__ Wih1, const float* __restrict__ Whh1,
    const float* __restrict__ bih1, const float* __restrict__ bhh1,
    const float* __restrict__ Wfc,  const float* __restrict__ bfc,
    float* __restrict__ out, char* __restrict__ ws)
{
    int*   flags = (int*)ws;                    // [16][16], poison 0xAA.. < 0: safe
    short* h0buf = (short*)(ws + 1024);         // [2][16][16][256] bf16
    short* h1buf = h0buf + 2 * 16 * 16 * 256;   // [2][16][16][256] bf16

    const int blk   = blockIdx.x;
    const int grp   = ((blk & 7) << 1) | ((blk >> 3) & 1); // batch-group 0..15
    const int chunk = blk >> 4;                            // hidden-chunk 0..15
    const int tid   = threadIdx.x;
    const int lane  = tid & 63;
    const int wave  = tid >> 6;      // gate index: 0=i 1=f 2=g 3=o
    const int quad  = lane >> 4;
    const int nn    = lane & 15;     // W-row within 16-row tile (= hidden unit in chunk)

    __shared__ short A0[16][328];    // [m][ x(64) | h0(256) ] + pad (rows 656B, 16B-mult)
    __shared__ short A1[16][520];    // [m][ h0(256) | h1(256) ] + pad
    __shared__ float gbuf[2][4][16][16];
    __shared__ float red[16][16];
    __shared__ float ldspad[5120];   // occupancy limiter: total ~56 KB -> max 2 wg/CU

    // zero A buffers (h0[-1] = 0, h1[-1] region unused until overwritten with zeros)
    for (int i = tid; i < 16 * 328; i += 256) (&A0[0][0])[i] = 0;
    for (int i = tid; i < 16 * 520; i += 256) (&A1[0][0])[i] = 0;

    // ---- static weight fragments -> registers (B operand: W[n][k], n=lane&15, k=quad*8+j)
    const int wrow = wave * HDIM + chunk * 16 + nn;
    short8 w0f[10];   // layer0: kb 0..1 = Wih0 (K 0..63), kb 2..9 = Whh0 (K 64..319)
    short8 w1f[16];   // layer1: kb 0..7 = Wih1 (K 0..255), kb 8..15 = Whh1 (K 256..511)
#pragma unroll
    for (int kb = 0; kb < 10; ++kb)
#pragma unroll
        for (int j = 0; j < 8; ++j) {
            int k = kb * 32 + quad * 8 + j;
            float v = (k < 64) ? Wih0[wrow * IDIM + k] : Whh0[wrow * HDIM + (k - 64)];
            w0f[kb][j] = f2bf(v);
        }
#pragma unroll
    for (int kb = 0; kb < 16; ++kb)
#pragma unroll
        for (int j = 0; j < 8; ++j) {
            int k = kb * 32 + quad * 8 + j;
            float v = (k < 256) ? Wih1[wrow * HDIM + k] : Whh1[wrow * HDIM + (k - 256)];
            w1f[kb][j] = f2bf(v);
        }
    const float bias0 = bih0[wrow] + bhh0[wrow];
    const float bias1 = bih1[wrow] + bhh1[wrow];

    const int em = tid >> 4;   // elementwise batch row (0..15)
    const int ej = tid & 15;   // elementwise hidden unit within chunk
    float c0 = 0.0f, c1 = 0.0f;

    auto load_x = [&](int t) {
        const float4 v = *(const float4*)&x[((size_t)(grp * 16 + em) * TT + t) * IDIM + ej * 4];
        short4v sv;
        sv[0] = f2bf(v.x); sv[1] = f2bf(v.y); sv[2] = f2bf(v.z); sv[3] = f2bf(v.w);
        *(short4v*)&A0[em][ej * 4] = sv;
    };

    __syncthreads();
    load_x(0);
    __syncthreads();

    // super-step s: layer0 computes h0[s] (s<T); layer1 computes h1[s-1] (s>=1)
    for (int s = 0; s <= TT; ++s) {
        const int par = s & 1;

        if (s < TT) {
            f32x4 acc = {0.f, 0.f, 0.f, 0.f};
#pragma unroll
            for (int kb = 0; kb < 10; ++kb) {
                short8 a = *(const short8*)&A0[nn][kb * 32 + quad * 8];
                acc = __builtin_amdgcn_mfma_f32_16x16x32_bf16(a, w0f[kb], acc, 0, 0, 0);
            }
#pragma unroll
            for (int r = 0; r < 4; ++r)
                gbuf[0][wave][quad * 4 + r][nn] = acc[r] + bias0;
        }
        if (s >= 1) {
            f32x4 acc = {0.f, 0.f, 0.f, 0.f};
#pragma unroll
            for (int kb = 0; kb < 16; ++kb) {
                short8 a = *(const short8*)&A1[nn][kb * 32 + quad * 8];
                acc = __builtin_amdgcn_mfma_f32_16x16x32_bf16(a, w1f[kb], acc, 0, 0, 0);
            }
#pragma unroll
            for (int r = 0; r < 4; ++r)
                gbuf[1][wave][quad * 4 + r][nn] = acc[r] + bias1;
        }
        __syncthreads();

        // elementwise LSTM cell updates; write own h-chunk to global exchange buffer
        if (s < TT) {
            float gi = sigm (gbuf[0][0][em][ej]);
            float gf = sigm (gbuf[0][1][em][ej]);
            float gg = tanh_(gbuf[0][2][em][ej]);
            float go = sigm (gbuf[0][3][em][ej]);
            c0 = gf * c0 + gi * gg;
            float h = go * tanh_(c0);
            h0buf[((par * 16 + grp) * 16 + em) * 256 + chunk * 16 + ej] = f2bf(h);
        }
        if (s >= 1) {
            float gi = sigm (gbuf[1][0][em][ej]);
            float gf = sigm (gbuf[1][1][em][ej]);
            float gg = tanh_(gbuf[1][2][em][ej]);
            float go = sigm (gbuf[1][3][em][ej]);
            c1 = gf * c1 + gi * gg;
            float h = go * tanh_(c1);
            h1buf[((par * 16 + grp) * 16 + em) * 256 + chunk * 16 + ej] = f2bf(h);
        } else {
            // s==0: publish h1[-1] = 0 so readers get zeros at s==1
            h1buf[((par * 16 + grp) * 16 + em) * 256 + chunk * 16 + ej] = 0;
        }
        __threadfence();           // make h stores device-visible
        __syncthreads();           // all threads' stores+fences done
        if (tid == 0)
            __hip_atomic_store(&flags[grp * 16 + chunk], s + 1,
                               __ATOMIC_RELEASE, __HIP_MEMORY_SCOPE_AGENT);

        if (s + 1 < TT) load_x(s + 1);   // overlap x prefetch with the spin

        if (tid < 16) {
            while (__hip_atomic_load(&flags[grp * 16 + tid],
                                     __ATOMIC_ACQUIRE, __HIP_MEMORY_SCOPE_AGENT) < s + 1) {}
        }
        __syncthreads();

        // gather full h vectors for next super-step
        if (s < TT) {
            const short8* src = (const short8*)&h0buf[((par * 16 + grp) * 16 + em) * 256 + ej * 16];
            short8 v0 = src[0], v1 = src[1];
            *(short8*)&A0[em][64 + ej * 16]     = v0;
            *(short8*)&A0[em][64 + ej * 16 + 8] = v1;
            *(short8*)&A1[em][ej * 16]          = v0;
            *(short8*)&A1[em][ej * 16 + 8]      = v1;
        }
        if (s >= 1) {
            const short8* src = (const short8*)&h1buf[((par * 16 + grp) * 16 + em) * 256 + ej * 16];
            *(short8*)&A1[em][256 + ej * 16]     = src[0];
            *(short8*)&A1[em][256 + ej * 16 + 8] = src[1];
        }
        __syncthreads();
    }

    // FC epilogue: A1[:,256..511] holds h1[T-1] (bf16)
    {
        float part = 0.f;
#pragma unroll
        for (int kk = 0; kk < 16; ++kk) {
            int k = ej * 16 + kk;
            part += bf2f(A1[em][256 + k]) * Wfc[k];
        }
        red[em][ej] = part;
    }
    __syncthreads();
    if (chunk == 0 && tid < 16) {
        float sum = bfc[0];
#pragma unroll
        for (int c = 0; c < 16; ++c) sum += red[tid][c];
        out[grp * 16 + tid] = sum;
    }

    // keep ldspad allocated (occupancy cap); never true at runtime
    if (gridDim.x > 100000) { ldspad[tid] = bias0; out[0] = ldspad[255 - tid]; }
}

extern "C" void kernel_launch(void* const* d_in, const int* in_sizes, int n_in,
                              void* d_out, int out_size, void* d_ws, size_t ws_size,
                              hipStream_t stream) {
    (void)in_sizes; (void)n_in; (void)out_size; (void)ws_size;
    const float* x    = (const float*)d_in[0];
    const float* Wih0 = (const float*)d_in[1];
    const float* Whh0 = (const float*)d_in[2];
    const float* bih0 = (const float*)d_in[3];
    const float* bhh0 = (const float*)d_in[4];
    const float* Wih1 = (const float*)d_in[5];
    const float* Whh1 = (const float*)d_in[6];
    const float* bih1 = (const float*)d_in[7];
    const float* bhh1 = (const float*)d_in[8];
    const float* Wfc  = (const float*)d_in[9];
    const float* bfc  = (const float*)d_in[10];

    lstm_fused<<<256, 256, 0, stream>>>(x, Wih0, Whh0, bih0, bhh0,
                                        Wih1, Whh1, bih1, bhh1, Wfc, bfc,
                                        (float*)d_out, (char*)d_ws);
}

// Round 2
// 1806.708 us; speedup vs baseline: 6.9426x; 6.9426x over previous
//
#include <hip/hip_runtime.h>

#define TT   512
#define IDIM 64
#define HDIM 256

typedef short  short8  __attribute__((ext_vector_type(8)));
typedef short  short4v __attribute__((ext_vector_type(4)));
typedef float  f32x4   __attribute__((ext_vector_type(4)));
typedef unsigned long long u64;

__device__ __forceinline__ short f2bf(float f) {
    unsigned u = __float_as_uint(f);
    u = u + 0x7FFFu + ((u >> 16) & 1u);   // round-to-nearest-even
    return (short)(u >> 16);
}
__device__ __forceinline__ float bf2f(short h) {
    return __uint_as_float(((unsigned)(unsigned short)h) << 16);
}
__device__ __forceinline__ float sigm(float x)  { return 1.0f / (1.0f + __expf(-x)); }
__device__ __forceinline__ float tanh_(float x) { return 2.0f / (1.0f + __expf(-2.0f * x)) - 1.0f; }

// 256 persistent workgroups = 16 batch-groups (16 rows) x 16 hidden-chunks (16 units).
// Cross-wg h exchange: relaxed agent-scope atomics only (sc1 -> coherent LLC point,
// NO fences -> no L2 writeback storms). Ordering h-data < flag via wave-0 funnel +
// s_waitcnt vmcnt(0) between data stores and flag store.
__global__ __launch_bounds__(256, 1) void lstm_fused(
    const float* __restrict__ x,
    const float* __restrict__ Wih0, const float* __restrict__ Whh0,
    const float* __restrict__ bih0, const float* __restrict__ bhh0,
    const float* __restrict__ Wih1, const float* __restrict__ Whh1,
    const float* __restrict__ bih1, const float* __restrict__ bhh1,
    const float* __restrict__ Wfc,  const float* __restrict__ bfc,
    float* __restrict__ out, char* __restrict__ ws)
{
    int*   flags = (int*)ws;                    // [16][16], poison 0xAA.. < 0: safe
    short* h0buf = (short*)(ws + 1024);         // [2][16][16][256] bf16
    short* h1buf = h0buf + 2 * 16 * 16 * 256;   // [2][16][16][256] bf16

    const int blk   = blockIdx.x;
    const int grp   = ((blk & 7) << 1) | ((blk >> 3) & 1); // batch-group 0..15
    const int chunk = blk >> 4;                            // hidden-chunk 0..15
    const int tid   = threadIdx.x;
    const int lane  = tid & 63;
    const int wave  = tid >> 6;      // gate index: 0=i 1=f 2=g 3=o
    const int quad  = lane >> 4;
    const int nn    = lane & 15;     // W-row within 16-row tile (= hidden unit in chunk)

    __shared__ short A0[16][328];    // [m][ x(64) | h0(256) ] + pad (rows 656B, 16B-mult)
    __shared__ short A1[16][520];    // [m][ h0(256) | h1(256) ] + pad
    __shared__ float gbuf[2][4][16][16];
    __shared__ float red[16][16];
    __shared__ __align__(16) short hls[2][16][16];  // h staging for wave-0 atomic funnel
    __shared__ float ldspad[5120];   // occupancy limiter: ~57 KB -> 1-2 wg/CU

    // zero A buffers (h0[-1] = 0, h1[-1] = 0 for the s==1 layer1 step)
    for (int i = tid; i < 16 * 328; i += 256) (&A0[0][0])[i] = 0;
    for (int i = tid; i < 16 * 520; i += 256) (&A1[0][0])[i] = 0;

    // ---- static weight fragments -> registers (B operand: W[n][k], n=lane&15, k=quad*8+j)
    const int wrow = wave * HDIM + chunk * 16 + nn;
    short8 w0f[10];   // layer0: kb 0..1 = Wih0 (K 0..63), kb 2..9 = Whh0 (K 64..319)
    short8 w1f[16];   // layer1: kb 0..7 = Wih1 (K 0..255), kb 8..15 = Whh1 (K 256..511)
#pragma unroll
    for (int kb = 0; kb < 10; ++kb)
#pragma unroll
        for (int j = 0; j < 8; ++j) {
            int k = kb * 32 + quad * 8 + j;
            float v = (k < 64) ? Wih0[wrow * IDIM + k] : Whh0[wrow * HDIM + (k - 64)];
            w0f[kb][j] = f2bf(v);
        }
#pragma unroll
    for (int kb = 0; kb < 16; ++kb)
#pragma unroll
        for (int j = 0; j < 8; ++j) {
            int k = kb * 32 + quad * 8 + j;
            float v = (k < 256) ? Wih1[wrow * HDIM + k] : Whh1[wrow * HDIM + (k - 256)];
            w1f[kb][j] = f2bf(v);
        }
    const float bias0 = bih0[wrow] + bhh0[wrow];
    const float bias1 = bih1[wrow] + bhh1[wrow];

    const int em = tid >> 4;   // elementwise batch row (0..15)
    const int ej = tid & 15;   // elementwise hidden unit within chunk
    float c0 = 0.0f, c1 = 0.0f;

    auto load_x = [&](int t) {
        const float4 v = *(const float4*)&x[((size_t)(grp * 16 + em) * TT + t) * IDIM + ej * 4];
        short4v sv;
        sv[0] = f2bf(v.x); sv[1] = f2bf(v.y); sv[2] = f2bf(v.z); sv[3] = f2bf(v.w);
        *(short4v*)&A0[em][ej * 4] = sv;
    };

    __syncthreads();
    load_x(0);
    __syncthreads();

    // super-step s: layer0 computes h0[s] (s<T); layer1 computes h1[s-1] (s>=1)
    for (int s = 0; s <= TT; ++s) {
        const int par = s & 1;

        if (s < TT) {
            f32x4 acc = {0.f, 0.f, 0.f, 0.f};
#pragma unroll
            for (int kb = 0; kb < 10; ++kb) {
                short8 a = *(const short8*)&A0[nn][kb * 32 + quad * 8];
                acc = __builtin_amdgcn_mfma_f32_16x16x32_bf16(a, w0f[kb], acc, 0, 0, 0);
            }
#pragma unroll
            for (int r = 0; r < 4; ++r)
                gbuf[0][wave][quad * 4 + r][nn] = acc[r] + bias0;
        }
        if (s >= 1) {
            f32x4 acc = {0.f, 0.f, 0.f, 0.f};
#pragma unroll
            for (int kb = 0; kb < 16; ++kb) {
                short8 a = *(const short8*)&A1[nn][kb * 32 + quad * 8];
                acc = __builtin_amdgcn_mfma_f32_16x16x32_bf16(a, w1f[kb], acc, 0, 0, 0);
            }
#pragma unroll
            for (int r = 0; r < 4; ++r)
                gbuf[1][wave][quad * 4 + r][nn] = acc[r] + bias1;
        }
        __syncthreads();

        // elementwise LSTM cell updates -> stage h in LDS (bf16)
        if (s < TT) {
            float gi = sigm (gbuf[0][0][em][ej]);
            float gf = sigm (gbuf[0][1][em][ej]);
            float gg = tanh_(gbuf[0][2][em][ej]);
            float go = sigm (gbuf[0][3][em][ej]);
            c0 = gf * c0 + gi * gg;
            hls[0][em][ej] = f2bf(go * tanh_(c0));
        }
        if (s >= 1) {
            float gi = sigm (gbuf[1][0][em][ej]);
            float gf = sigm (gbuf[1][1][em][ej]);
            float gg = tanh_(gbuf[1][2][em][ej]);
            float go = sigm (gbuf[1][3][em][ej]);
            c1 = gf * c1 + gi * gg;
            hls[1][em][ej] = f2bf(go * tanh_(c1));
        } else {
            hls[1][em][ej] = 0;
        }
        __syncthreads();   // hls complete

        // wave-0 funnel: publish both h chunks as relaxed agent atomics, then flag.
        // s_waitcnt vmcnt(0) orders data < flag within wave 0. No fences anywhere.
        if (tid < 64) {
            const int wm = tid >> 2;           // 0..15 batch row
            const int wp = tid & 3;            // 0..3  (4 shorts = 8B each)
            const u64 v0 = *(const u64*)&hls[0][wm][wp * 4];
            const u64 v1 = *(const u64*)&hls[1][wm][wp * 4];
            const size_t base = ((size_t)(par * 16 + grp) * 16 + wm) * 256 + chunk * 16 + wp * 4;
            __hip_atomic_store((u64*)&h0buf[base], v0, __ATOMIC_RELAXED, __HIP_MEMORY_SCOPE_AGENT);
            __hip_atomic_store((u64*)&h1buf[base], v1, __ATOMIC_RELAXED, __HIP_MEMORY_SCOPE_AGENT);
            asm volatile("s_waitcnt vmcnt(0)" ::: "memory");
            if (tid == 0)
                __hip_atomic_store(&flags[grp * 16 + chunk], s + 1,
                                   __ATOMIC_RELAXED, __HIP_MEMORY_SCOPE_AGENT);
        }

        if (s + 1 < TT) load_x(s + 1);   // overlap x prefetch with the spin

        if (tid < 16) {
            while (__hip_atomic_load(&flags[grp * 16 + tid],
                                     __ATOMIC_RELAXED, __HIP_MEMORY_SCOPE_AGENT) < s + 1) {}
        }
        __syncthreads();

        // gather full h vectors for next super-step (relaxed agent atomic loads -> LLC)
        if (s < TT) {
            const size_t base = ((size_t)(par * 16 + grp) * 16 + em) * 256 + ej * 16;
            const u64* s0 = (const u64*)&h0buf[base];
            u64 v0 = __hip_atomic_load(&s0[0], __ATOMIC_RELAXED, __HIP_MEMORY_SCOPE_AGENT);
            u64 v1 = __hip_atomic_load(&s0[1], __ATOMIC_RELAXED, __HIP_MEMORY_SCOPE_AGENT);
            u64 v2 = __hip_atomic_load(&s0[2], __ATOMIC_RELAXED, __HIP_MEMORY_SCOPE_AGENT);
            u64 v3 = __hip_atomic_load(&s0[3], __ATOMIC_RELAXED, __HIP_MEMORY_SCOPE_AGENT);
            u64* d0 = (u64*)&A0[em][64 + ej * 16];
            u64* d1 = (u64*)&A1[em][ej * 16];
            d0[0] = v0; d0[1] = v1; d0[2] = v2; d0[3] = v3;
            d1[0] = v0; d1[1] = v1; d1[2] = v2; d1[3] = v3;
        }
        if (s >= 1) {
            const size_t base = ((size_t)(par * 16 + grp) * 16 + em) * 256 + ej * 16;
            const u64* s1 = (const u64*)&h1buf[base];
            u64 v0 = __hip_atomic_load(&s1[0], __ATOMIC_RELAXED, __HIP_MEMORY_SCOPE_AGENT);
            u64 v1 = __hip_atomic_load(&s1[1], __ATOMIC_RELAXED, __HIP_MEMORY_SCOPE_AGENT);
            u64 v2 = __hip_atomic_load(&s1[2], __ATOMIC_RELAXED, __HIP_MEMORY_SCOPE_AGENT);
            u64 v3 = __hip_atomic_load(&s1[3], __ATOMIC_RELAXED, __HIP_MEMORY_SCOPE_AGENT);
            u64* d2 = (u64*)&A1[em][256 + ej * 16];
            d2[0] = v0; d2[1] = v1; d2[2] = v2; d2[3] = v3;
        }
        __syncthreads();
    }

    // FC epilogue: A1[:,256..511] holds h1[T-1] (bf16)
    {
        float part = 0.f;
#pragma unroll
        for (int kk = 0; kk < 16; ++kk) {
            int k = ej * 16 + kk;
            part += bf2f(A1[em][256 + k]) * Wfc[k];
        }
        red[em][ej] = part;
    }
    __syncthreads();
    if (chunk == 0 && tid < 16) {
        float sum = bfc[0];
#pragma unroll
        for (int c = 0; c < 16; ++c) sum += red[tid][c];
        out[grp * 16 + tid] = sum;
    }

    // keep ldspad allocated (occupancy cap); never true at runtime
    if (gridDim.x > 100000) { ldspad[tid] = bias0; out[0] = ldspad[255 - tid]; }
}

extern "C" void kernel_launch(void* const* d_in, const int* in_sizes, int n_in,
                              void* d_out, int out_size, void* d_ws, size_t ws_size,
                              hipStream_t stream) {
    (void)in_sizes; (void)n_in; (void)out_size; (void)ws_size;
    const float* x    = (const float*)d_in[0];
    const float* Wih0 = (const float*)d_in[1];
    const float* Whh0 = (const float*)d_in[2];
    const float* bih0 = (const float*)d_in[3];
    const float* bhh0 = (const float*)d_in[4];
    const float* Wih1 = (const float*)d_in[5];
    const float* Whh1 = (const float*)d_in[6];
    const float* bih1 = (const float*)d_in[7];
    const float* bhh1 = (const float*)d_in[8];
    const float* Wfc  = (const float*)d_in[9];
    const float* bfc  = (const float*)d_in[10];

    lstm_fused<<<256, 256, 0, stream>>>(x, Wih0, Whh0, bih0, bhh0,
                                        Wih1, Whh1, bih1, bhh1, Wfc, bfc,
                                        (float*)d_out, (char*)d_ws);
}